// Round 6
// baseline (179.391 us; speedup 1.0000x reference)
//
#include <hip/hip_runtime.h>
#include <hip/hip_bf16.h>

#define N_NODES 8192
#define N_EDGES 262144
#define F_INDIM 128
#define HID 256
#define F_OUT 128
#define N_GRAPHS 64
#define WPR (N_NODES / 32)   // 256 words per bitmask row
#define CAP 160              // max supported degree (Poisson(64), 12 sigma headroom)

// ---------------------------------------------------------------------------
// 0. Cast X (f32) -> Xh (bf16) once; gather table becomes 2 MB.
// ---------------------------------------------------------------------------
__global__ __launch_bounds__(256) void cast_x(const float* __restrict__ X,
                                              __hip_bfloat16* __restrict__ Xh) {
    int idx = blockIdx.x * 256 + threadIdx.x;
    Xh[idx] = __float2bfloat16(X[idx]);
}

// ---------------------------------------------------------------------------
// 1. Edge scatter into symmetric bitmask (dedup by construction)  [R2 proven]
// ---------------------------------------------------------------------------
__global__ __launch_bounds__(256) void scatter_edges(const int* __restrict__ ei,
                                                     unsigned int* __restrict__ mask) {
    int e = blockIdx.x * blockDim.x + threadIdx.x;
    if (e >= N_EDGES) return;
    int s = ei[e];
    int d = ei[N_EDGES + e];
    if ((unsigned)s >= N_NODES || (unsigned)d >= N_NODES) return;  // safety guard
    atomicOr(&mask[(size_t)s * WPR + (d >> 5)], 1u << (d & 31));
    atomicOr(&mask[(size_t)d * WPR + (s >> 5)], 1u << (s & 31));
}

// ---------------------------------------------------------------------------
// 2. Bitmask -> fixed-stride adjacency + deg + dis. One wave/row. [R2 proven]
// ---------------------------------------------------------------------------
__global__ __launch_bounds__(256) void build_adj(const unsigned int* __restrict__ mask,
                                                 int* __restrict__ adj,
                                                 int* __restrict__ deg,
                                                 float* __restrict__ dis) {
    int row = (blockIdx.x * blockDim.x + threadIdx.x) >> 6;
    int lane = threadIdx.x & 63;
    if (row >= N_NODES) return;
    const uint4* r = (const uint4*)(mask + (size_t)row * WPR);
    uint4 v = r[lane];
    int cnt = __popc(v.x) + __popc(v.y) + __popc(v.z) + __popc(v.w);
    int scan = cnt;  // inclusive scan across 64 lanes
    for (int off = 1; off < 64; off <<= 1) {
        int n = __shfl_up(scan, off);
        if (lane >= off) scan += n;
    }
    int tot = __shfl(scan, 63);
    int idx = scan - cnt;  // exclusive prefix = my write base
    int* ap = adj + (size_t)row * CAP;
    int wbase = lane << 7;  // lane*4 words * 32 bits
    unsigned int wd;
    wd = v.x; while (wd) { int b = __ffs(wd) - 1; wd &= wd - 1; if (idx < CAP) ap[idx] = wbase + b;      ++idx; }
    wd = v.y; while (wd) { int b = __ffs(wd) - 1; wd &= wd - 1; if (idx < CAP) ap[idx] = wbase + 32 + b; ++idx; }
    wd = v.z; while (wd) { int b = __ffs(wd) - 1; wd &= wd - 1; if (idx < CAP) ap[idx] = wbase + 64 + b; ++idx; }
    wd = v.w; while (wd) { int b = __ffs(wd) - 1; wd &= wd - 1; if (idx < CAP) ap[idx] = wbase + 96 + b; ++idx; }
    if (lane == 63) { deg[row] = tot; dis[row] = rsqrtf((float)(tot + 1)); }  // +1: identity
}

// ---------------------------------------------------------------------------
// 3. spmm_x + fused sv (bf16 gather table, f32 accumulate)
//    G[i][c] = dis_i*(dis_i*Xh[i][c] + sum_j dis_j*Xh[j][c]);  sv = (A_hat@1)
// ---------------------------------------------------------------------------
__global__ __launch_bounds__(128) void spmm_x(const int* __restrict__ adj,
                                              const int* __restrict__ deg,
                                              const __hip_bfloat16* __restrict__ Xh,
                                              const float* __restrict__ dis,
                                              float* __restrict__ G,
                                              float* __restrict__ sv) {
    int i = blockIdx.x;
    int c = threadIdx.x;
    int d = deg[i]; if (d > CAP) d = CAP;
    __shared__ int nb[CAP];
    __shared__ float nbd[CAP];
    __shared__ float red[2];
    float p = 0.0f;
    for (int t = c; t < d; t += 128) {
        int j = adj[(size_t)i * CAP + t];
        float dj = dis[j];
        nb[t] = j; nbd[t] = dj;
        p += dj;
    }
    for (int off = 32; off; off >>= 1) p += __shfl_down(p, off);
    if ((c & 63) == 0) red[c >> 6] = p;
    __syncthreads();  // covers nb, nbd, red
    float di = dis[i];
    if (c == 0) sv[i] = di * (di + red[0] + red[1]);
    float a0 = di * __bfloat162float(Xh[(size_t)i * F_INDIM + c]);  // identity
    float a1 = 0.f, a2 = 0.f, a3 = 0.f, a4 = 0.f, a5 = 0.f, a6 = 0.f, a7 = 0.f;
    int k = 0;
    for (; k + 8 <= d; k += 8) {
        int j0 = nb[k],   j1 = nb[k+1], j2 = nb[k+2], j3 = nb[k+3];
        int j4 = nb[k+4], j5 = nb[k+5], j6 = nb[k+6], j7 = nb[k+7];
        a0 += nbd[k]   * __bfloat162float(Xh[(size_t)j0 * F_INDIM + c]);
        a1 += nbd[k+1] * __bfloat162float(Xh[(size_t)j1 * F_INDIM + c]);
        a2 += nbd[k+2] * __bfloat162float(Xh[(size_t)j2 * F_INDIM + c]);
        a3 += nbd[k+3] * __bfloat162float(Xh[(size_t)j3 * F_INDIM + c]);
        a4 += nbd[k+4] * __bfloat162float(Xh[(size_t)j4 * F_INDIM + c]);
        a5 += nbd[k+5] * __bfloat162float(Xh[(size_t)j5 * F_INDIM + c]);
        a6 += nbd[k+6] * __bfloat162float(Xh[(size_t)j6 * F_INDIM + c]);
        a7 += nbd[k+7] * __bfloat162float(Xh[(size_t)j7 * F_INDIM + c]);
    }
    for (; k < d; ++k) a0 += nbd[k] * __bfloat162float(Xh[(size_t)nb[k] * F_INDIM + c]);
    float acc = ((a0 + a1) + (a2 + a3)) + ((a4 + a5) + (a6 + a7));
    G[(size_t)i * F_INDIM + c] = di * acc;
}

// ---------------------------------------------------------------------------
// 4. GEMM1 (8 rows/block): H = relu(G@W1 + sv*b1)
// ---------------------------------------------------------------------------
__global__ __launch_bounds__(256) void gemm1_v4(const float* __restrict__ G,
                                                const float* __restrict__ W1,
                                                const float* __restrict__ b1,
                                                const float* __restrict__ sv,
                                                float* __restrict__ H) {
    int i0 = blockIdx.x * 8;
    int t = threadIdx.x;
    __shared__ float xs[8][F_INDIM];
    for (int v = t; v < 8 * F_INDIM; v += 256)
        xs[v >> 7][v & 127] = G[(size_t)(i0 + (v >> 7)) * F_INDIM + (v & 127)];
    __syncthreads();
    float bt = b1[t];
    float a0 = 0.f, a1 = 0.f, a2 = 0.f, a3 = 0.f, a4 = 0.f, a5 = 0.f, a6 = 0.f, a7 = 0.f;
#pragma unroll 8
    for (int k = 0; k < F_INDIM; ++k) {
        float w = W1[(size_t)k * HID + t];
        a0 += xs[0][k] * w; a1 += xs[1][k] * w; a2 += xs[2][k] * w; a3 += xs[3][k] * w;
        a4 += xs[4][k] * w; a5 += xs[5][k] * w; a6 += xs[6][k] * w; a7 += xs[7][k] * w;
    }
#define EPI1(R, ACC) H[(size_t)(i0 + R) * HID + t] = fmaxf(ACC + sv[i0 + R] * bt, 0.0f);
    EPI1(0, a0) EPI1(1, a1) EPI1(2, a2) EPI1(3, a3)
    EPI1(4, a4) EPI1(5, a5) EPI1(6, a6) EPI1(7, a7)
#undef EPI1
}

// ---------------------------------------------------------------------------
// 5. GEMM2 (8 rows/block): M2ph[i][t] = bf16( dis[i]*(H[i,:]@W2[:,t] + b2[t]) )
// ---------------------------------------------------------------------------
__global__ __launch_bounds__(128) void gemm2_v4(const float* __restrict__ H,
                                                const float* __restrict__ W2,
                                                const float* __restrict__ b2,
                                                const float* __restrict__ dis,
                                                __hip_bfloat16* __restrict__ M2ph) {
    int i0 = blockIdx.x * 8;
    int t = threadIdx.x;
    __shared__ float hs[8][HID];
    for (int v = t; v < 8 * HID; v += 128)
        hs[v >> 8][v & 255] = H[(size_t)(i0 + (v >> 8)) * HID + (v & 255)];
    __syncthreads();
    float bt = b2[t];
    float a0 = bt, a1 = bt, a2 = bt, a3 = bt, a4 = bt, a5 = bt, a6 = bt, a7 = bt;
#pragma unroll 8
    for (int k = 0; k < HID; ++k) {
        float w = W2[(size_t)k * F_OUT + t];
        a0 += hs[0][k] * w; a1 += hs[1][k] * w; a2 += hs[2][k] * w; a3 += hs[3][k] * w;
        a4 += hs[4][k] * w; a5 += hs[5][k] * w; a6 += hs[6][k] * w; a7 += hs[7][k] * w;
    }
#define EPI2(R, ACC) M2ph[(size_t)(i0 + R) * F_OUT + t] = __float2bfloat16(dis[i0 + R] * ACC);
    EPI2(0, a0) EPI2(1, a1) EPI2(2, a2) EPI2(3, a3)
    EPI2(4, a4) EPI2(5, a5) EPI2(6, a6) EPI2(7, a7)
#undef EPI2
}

// ---------------------------------------------------------------------------
// 6. SpMM2 (bf16 gather table, f32 accumulate)
// ---------------------------------------------------------------------------
__global__ __launch_bounds__(128) void spmm2(const int* __restrict__ adj,
                                             const int* __restrict__ deg,
                                             const __hip_bfloat16* __restrict__ M2ph,
                                             const float* __restrict__ dis,
                                             float* __restrict__ H2) {
    int i = blockIdx.x;
    int c = threadIdx.x;
    int d = deg[i]; if (d > CAP) d = CAP;
    __shared__ int nb[CAP];
    for (int t = c; t < d; t += 128) nb[t] = adj[(size_t)i * CAP + t];
    __syncthreads();
    float a0 = __bfloat162float(M2ph[(size_t)i * F_OUT + c]);  // identity term
    float a1 = 0.f, a2 = 0.f, a3 = 0.f, a4 = 0.f, a5 = 0.f, a6 = 0.f, a7 = 0.f;
    int k = 0;
    for (; k + 8 <= d; k += 8) {
        int j0 = nb[k],   j1 = nb[k+1], j2 = nb[k+2], j3 = nb[k+3];
        int j4 = nb[k+4], j5 = nb[k+5], j6 = nb[k+6], j7 = nb[k+7];
        a0 += __bfloat162float(M2ph[(size_t)j0 * F_OUT + c]);
        a1 += __bfloat162float(M2ph[(size_t)j1 * F_OUT + c]);
        a2 += __bfloat162float(M2ph[(size_t)j2 * F_OUT + c]);
        a3 += __bfloat162float(M2ph[(size_t)j3 * F_OUT + c]);
        a4 += __bfloat162float(M2ph[(size_t)j4 * F_OUT + c]);
        a5 += __bfloat162float(M2ph[(size_t)j5 * F_OUT + c]);
        a6 += __bfloat162float(M2ph[(size_t)j6 * F_OUT + c]);
        a7 += __bfloat162float(M2ph[(size_t)j7 * F_OUT + c]);
    }
    for (; k < d; ++k) a0 += __bfloat162float(M2ph[(size_t)nb[k] * F_OUT + c]);
    float acc = ((a0 + a1) + (a2 + a3)) + ((a4 + a5) + (a6 + a7));
    H2[(size_t)i * F_OUT + c] = dis[i] * acc;
}

// ---------------------------------------------------------------------------
// 7. Pool stage A: partial sums, grid (graph, 16 chunks)  [R4 verbatim]
// ---------------------------------------------------------------------------
__global__ __launch_bounds__(128) void pool_a(const float* __restrict__ H2,
                                              const int* __restrict__ batch,
                                              float* __restrict__ part) {
    int g = blockIdx.x, s = blockIdx.y, c = threadIdx.x;
    int lo = 0, hi = N_NODES;
    while (lo < hi) { int m = (lo + hi) >> 1; if (batch[m] < g) lo = m + 1; else hi = m; }
    int start = lo;
    hi = N_NODES;
    while (lo < hi) { int m = (lo + hi) >> 1; if (batch[m] < g + 1) lo = m + 1; else hi = m; }
    int end = lo;
    int len = end - start;
    int chunk = (len + 15) >> 4;
    int a = start + s * chunk;
    int b = a + chunk; if (b > end) b = end;
    float sum = 0.0f;
    for (int i = a; i < b; ++i) sum += H2[(size_t)i * F_OUT + c];
    part[((size_t)g * 16 + s) * F_OUT + c] = sum;
}

// ---------------------------------------------------------------------------
// 8. Pool stage B: combine 16 partials, divide by count  [R4 verbatim]
// ---------------------------------------------------------------------------
__global__ __launch_bounds__(128) void pool_b(const float* __restrict__ part,
                                              const int* __restrict__ batch,
                                              float* __restrict__ out) {
    int g = blockIdx.x, c = threadIdx.x;
    int lo = 0, hi = N_NODES;
    while (lo < hi) { int m = (lo + hi) >> 1; if (batch[m] < g) lo = m + 1; else hi = m; }
    int start = lo;
    hi = N_NODES;
    while (lo < hi) { int m = (lo + hi) >> 1; if (batch[m] < g + 1) lo = m + 1; else hi = m; }
    int cnt = lo - start;
    float s = 0.0f;
#pragma unroll
    for (int t = 0; t < 16; ++t) s += part[((size_t)g * 16 + t) * F_OUT + c];
    out[(size_t)g * F_OUT + c] = s / (float)(cnt > 0 ? cnt : 1);
}

// ---------------------------------------------------------------------------
extern "C" void kernel_launch(void* const* d_in, const int* in_sizes, int n_in,
                              void* d_out, int out_size, void* d_ws, size_t ws_size,
                              hipStream_t stream) {
    const float* X  = (const float*)d_in[0];
    const float* W1 = (const float*)d_in[1];
    const float* b1 = (const float*)d_in[2];
    const float* W2 = (const float*)d_in[3];
    const float* b2 = (const float*)d_in[4];
    const int* ei    = (const int*)d_in[5];
    const int* batch = (const int*)d_in[6];
    float* out = (float*)d_out;

    char* ws = (char*)d_ws;
    // [0, 8MB): mask during build; later M2ph (2MB) at 0 and H2 (4MB) at +4MB
    unsigned int* mask   = (unsigned int*)(ws);
    __hip_bfloat16* M2ph = (__hip_bfloat16*)(ws);    // alias: written after mask dead
    float* H2  = (float*)(ws + 4194304);             // 4 MB (8192x128 f32)
    float* G   = (float*)(ws + 8388608);             // 4 MB (8192x128 f32)
    __hip_bfloat16* Xh = (__hip_bfloat16*)(ws + 12582912);  // 2 MB (8192x128 bf16)
    float* part = (float*)(ws + 14680064);           // 512 KB (64x16x128)
    float* H   = (float*)(ws + 16777216);            // 8 MB (8192x256 f32)
    int*   adj = (int*)(ws + 25165824);              // 5.25 MB (8192x160 int)
    int*   deg = (int*)(ws + 30408704);              // 32 KB
    float* dis = (float*)(ws + 30441472);            // 32 KB
    float* sv  = (float*)(ws + 30474240);            // 32 KB

    cast_x<<<(N_NODES * F_INDIM) / 256, 256, 0, stream>>>(X, Xh);
    hipMemsetAsync(mask, 0, (size_t)N_NODES * WPR * sizeof(unsigned int), stream);
    scatter_edges<<<N_EDGES / 256, 256, 0, stream>>>(ei, mask);
    build_adj<<<N_NODES / 4, 256, 0, stream>>>(mask, adj, deg, dis);
    spmm_x<<<N_NODES, 128, 0, stream>>>(adj, deg, Xh, dis, G, sv);
    gemm1_v4<<<N_NODES / 8, 256, 0, stream>>>(G, W1, b1, sv, H);
    gemm2_v4<<<N_NODES / 8, 128, 0, stream>>>(H, W2, b2, dis, M2ph);
    spmm2<<<N_NODES, 128, 0, stream>>>(adj, deg, M2ph, dis, H2);
    pool_a<<<dim3(N_GRAPHS, 16), 128, 0, stream>>>(H2, batch, part);
    pool_b<<<N_GRAPHS, 128, 0, stream>>>(part, batch, out);
}